// Round 4
// baseline (63.921 us; speedup 1.0000x reference)
//
#include <hip/hip_runtime.h>

// Problem constants (must match reference)
#define L_SZ 100000
#define K_DIM 128
#define B_SZ 16384
#define CS_SZ 8
#define NS_SZ 20
#define NEPOCH 10
#define LOG_SQRT_2PI 0.9189385332046727

// native clang vector type for nontemporal builtins
typedef float f32x4 __attribute__((ext_vector_type(4)));

// softplus(x) = max(x,0) + log(1 + exp(-|x|)); fast-math variant is fine:
// tolerance is ~2% relative on a ~2.6e7 loss.
__device__ __forceinline__ float softplus_f(float x) {
    return fmaxf(x, 0.0f) + __logf(1.0f + __expf(-fabsf(x)));
}

// ---- fused likelihood + prior kernel ---------------------------------------
// 4096 blocks x 256 threads (4 waves) = 16384 waves; one batch element per
// wave. Within a wave: 4 groups of 16 lanes; lane (g, j) holds dims
// j*8..j*8+7. Group g owns targets n = 4s+g (n=0 is the positive target).
// All 6 target rows are preloaded into registers (clamped index for the 3
// invalid n>=21 slots) so 6 gathers are in flight before the first reduce.
__global__ __launch_bounds__(256) void fused_kernel(
    const int* __restrict__ contexts, const int* __restrict__ targets,
    const int* __restrict__ neg_idx, const float* __restrict__ tW,
    const float* __restrict__ cW,
    double* __restrict__ pll, double* __restrict__ pprior)
{
    const int lane = threadIdx.x & 63;
    const int wave = threadIdx.x >> 6;
    const int j = lane & 15;      // position within 16-lane group
    const int g = lane >> 4;      // group 0..3

    const int n_mine = 4 * j + g;           // target this lane softpluses
    const bool valid = (n_mine < 21);
    const float sgn = (n_mine == 0) ? -1.0f : 1.0f;  // pos: softplus(-eta)

    // wave-uniform batch index -> SGPR so index loads become s_load
    const int b = __builtin_amdgcn_readfirstlane(blockIdx.x * 4 + wave);

    // ---- preload the 6 target rows for this group (independent gathers) ----
    float4 r0[6], r1[6];
    #pragma unroll
    for (int s = 0; s < 6; ++s) {
        const int n = 4 * s + g;
        int t;
        if (n == 0)       t = targets[b];
        else if (n < 21)  t = neg_idx[b * NS_SZ + (n - 1)];
        else              t = neg_idx[b * NS_SZ];   // clamped, masked later
        const float4* r = reinterpret_cast<const float4*>(
            &tW[(size_t)t * K_DIM + j * 8]);
        r0[s] = r[0]; r1[s] = r[1];
    }

    // ---- ctx_sum dims j*8..j*8+7 (same rows across the 4 groups) -----------
    float4 s0 = {0.f, 0.f, 0.f, 0.f}, s1 = {0.f, 0.f, 0.f, 0.f};
    #pragma unroll
    for (int c = 0; c < CS_SZ; ++c) {
        const int idx = contexts[b * CS_SZ + c];
        const float4* r = reinterpret_cast<const float4*>(
            &cW[(size_t)idx * K_DIM + j * 8]);
        const float4 a = r[0], d = r[1];
        s0.x += a.x; s0.y += a.y; s0.z += a.z; s0.w += a.w;
        s1.x += d.x; s1.y += d.y; s1.z += d.z; s1.w += d.w;
    }

    // ---- 6 dot products + 16-lane butterflies ------------------------------
    float lacc = 0.0f;
    float keep = 0.0f;
    #pragma unroll
    for (int s = 0; s < 6; ++s) {
        const float4 a = r0[s], d = r1[s];
        float p = a.x * s0.x + a.y * s0.y + a.z * s0.z + a.w * s0.w
                + d.x * s1.x + d.y * s1.y + d.z * s1.z + d.w * s1.w;
        p += __shfl_xor(p, 1, 16);
        p += __shfl_xor(p, 2, 16);
        p += __shfl_xor(p, 4, 16);
        p += __shfl_xor(p, 8, 16);
        keep = (j == s) ? p : keep;
    }
    lacc = valid ? softplus_f(sgn * keep) : 0.0f;

    // ---- prior phase: grid-stride sum of squares over both tables ----------
    const int NT4 = (L_SZ * K_DIM) / 4;          // 3,200,000
    const int NC4 = ((L_SZ + 1) * K_DIM) / 4;    // 3,200,032
    const int tid = blockIdx.x * blockDim.x + threadIdx.x;
    const int stride = gridDim.x * blockDim.x;

    float pacc = 0.0f;
    const f32x4* t4 = reinterpret_cast<const f32x4*>(tW);
    for (int i = tid; i < NT4; i += stride) {
        const f32x4 v = __builtin_nontemporal_load(&t4[i]);
        pacc += v.x * v.x + v.y * v.y + v.z * v.z + v.w * v.w;
    }
    const f32x4* c4 = reinterpret_cast<const f32x4*>(cW);
    for (int i = tid; i < NC4; i += stride) {
        const f32x4 v = __builtin_nontemporal_load(&c4[i]);
        pacc += v.x * v.x + v.y * v.y + v.z * v.z + v.w * v.w;
    }

    // ---- per-wave then per-block reduction ---------------------------------
    #pragma unroll
    for (int o = 32; o; o >>= 1) {
        lacc += __shfl_xor(lacc, o, 64);
        pacc += __shfl_xor(pacc, o, 64);
    }
    __shared__ float sl[4], sp[4];
    if (lane == 0) { sl[wave] = lacc; sp[wave] = pacc; }
    __syncthreads();
    if (threadIdx.x == 0) {
        pll[blockIdx.x]    = (double)(sl[0] + sl[1] + sl[2] + sl[3]);
        pprior[blockIdx.x] = (double)(sp[0] + sp[1] + sp[2] + sp[3]);
    }
}

// ---- finalize: reduce partials, assemble scalar loss ------------------------
__global__ __launch_bounds__(256) void finalize_kernel(
    const double* __restrict__ pll, int nll,
    const double* __restrict__ pprior, int nprior,
    float* __restrict__ out)
{
    double a = 0.0, p = 0.0;
    for (int i = threadIdx.x; i < nll; i += 256) a += pll[i];
    for (int i = threadIdx.x; i < nprior; i += 256) p += pprior[i];

    __shared__ double sA[256], sP[256];
    sA[threadIdx.x] = a; sP[threadIdx.x] = p;
    __syncthreads();
    for (int s = 128; s > 0; s >>= 1) {
        if (threadIdx.x < s) {
            sA[threadIdx.x] += sA[threadIdx.x + s];
            sP[threadIdx.x] += sP[threadIdx.x + s];
        }
        __syncthreads();
    }
    if (threadIdx.x == 0) {
        // loss = NEPOCH * sum(softplus terms) + 0.5*sum(x^2) + count*LOG_SQRT_2PI
        const double C = (double)((2LL * L_SZ + 1) * K_DIM) * LOG_SQRT_2PI;
        const double loss = (double)NEPOCH * sA[0] + 0.5 * sP[0] + C;
        out[0] = (float)loss;
    }
}

extern "C" void kernel_launch(void* const* d_in, const int* in_sizes, int n_in,
                              void* d_out, int out_size, void* d_ws, size_t ws_size,
                              hipStream_t stream) {
    const int*   contexts = (const int*)d_in[0];
    const int*   targets  = (const int*)d_in[1];
    const int*   neg_idx  = (const int*)d_in[2];
    const float* tW       = (const float*)d_in[3];
    const float* cW       = (const float*)d_in[4];
    float* out = (float*)d_out;

    double* pll    = (double*)d_ws;   // 4096 doubles
    double* pprior = pll + 4096;      // 4096 doubles

    fused_kernel<<<4096, 256, 0, stream>>>(contexts, targets, neg_idx,
                                           tW, cW, pll, pprior);
    finalize_kernel<<<1, 256, 0, stream>>>(pll, 4096, pprior, 4096, out);
}